// Round 7
// baseline (342.713 us; speedup 1.0000x reference)
//
#include <hip/hip_runtime.h>
#include <math.h>

#define B_ 8
#define T_ 1024
#define C_ 768
#define H_ 8
#define D_ 96
#define M_ (B_ * T_)     // 8192 tokens
#define N1_ (3 * C_)     // 2304
#define KD_ 768          // GEMM K (both GEMMs)
#define NKC 24           // K / 32

typedef __bf16 bf16x8 __attribute__((ext_vector_type(8)));
typedef float f32x4 __attribute__((ext_vector_type(4)));

__device__ __forceinline__ unsigned short f2bf(float f) {
  unsigned int u = __float_as_uint(f);
  u += 0x7FFF + ((u >> 16) & 1);          // round-to-nearest-even
  return (unsigned short)(u >> 16);
}

// async global->LDS, 16B per lane; LDS dest = uniform base + lane*16
__device__ __forceinline__ void load_lds16(const void* g, void* l) {
  __builtin_amdgcn_global_load_lds(
      (const __attribute__((address_space(1))) unsigned int*)g,
      (__attribute__((address_space(3))) unsigned int*)l, 16, 0, 0);
}

// ---------------------------------------------------------------------------
// fp32 -> bf16 elementwise (for x)
// ---------------------------------------------------------------------------
__global__ __launch_bounds__(256) void cvt_bf16_kernel(
    const float* __restrict__ in, unsigned short* __restrict__ out, int n) {
  int i = (blockIdx.x * 256 + threadIdx.x) * 4;
  if (i + 3 < n) {
    float4 v = *(const float4*)(in + i);
    ushort4 o;
    o.x = f2bf(v.x); o.y = f2bf(v.y); o.z = f2bf(v.z); o.w = f2bf(v.w);
    *(ushort4*)(out + i) = o;
  }
}

// ---------------------------------------------------------------------------
// W [Kd][Nd] fp32 -> WT [Nd][Kd] bf16
// ---------------------------------------------------------------------------
__global__ __launch_bounds__(256) void w_transpose_kernel(
    const float* __restrict__ W, unsigned short* __restrict__ WT,
    int Kd, int Nd) {
  __shared__ float Lt[32][33];
  const int r0 = blockIdx.x * 32;   // Kd
  const int c0 = blockIdx.y * 32;   // Nd
#pragma unroll
  for (int i = 0; i < 4; ++i) {
    int e = threadIdx.x + 256 * i;
    int r = e >> 5, c = e & 31;
    Lt[r][c] = W[(size_t)(r0 + r) * Nd + c0 + c];
  }
  __syncthreads();
#pragma unroll
  for (int i = 0; i < 4; ++i) {
    int e = threadIdx.x + 256 * i;
    int rr = e >> 5, cc = e & 31;
    WT[(size_t)(c0 + rr) * Kd + r0 + cc] = f2bf(Lt[cc][rr]);
  }
}

// ---------------------------------------------------------------------------
// V region of qkv [8192][2304] -> VT [bh=64][d=96][t=1024] bf16
// ---------------------------------------------------------------------------
__global__ __launch_bounds__(256) void v_transpose_kernel(
    const unsigned short* __restrict__ qkv, unsigned short* __restrict__ vt) {
  const int tid = threadIdx.x;
  const int token = blockIdx.x * 64 + (tid & 63);
  const int c = blockIdx.y * 4 + (tid >> 6);     // 0..95
  const int b = token >> 10, t = token & 1023;
  const int h = c / 12, cd = c % 12;
  const unsigned short* src =
      qkv + (size_t)token * N1_ + 2 * C_ + h * D_ + cd * 8;
  ushort4 a = *(const ushort4*)src;
  ushort4 b4 = *(const ushort4*)(src + 4);
  unsigned short v[8] = {a.x, a.y, a.z, a.w, b4.x, b4.y, b4.z, b4.w};
  size_t base = ((size_t)(b * H_ + h) * D_ + cd * 8) * T_ + t;
#pragma unroll
  for (int i = 0; i < 8; ++i) vt[base + (size_t)i * T_] = v[i];
}

// ---------------------------------------------------------------------------
// Barrier-free-K-loop bf16 MFMA GEMM (K=768 fixed).
// Block: 32-row M-panel x 384 cols, 256 thr. Whole A panel (32x768 = 48 KB)
// staged to LDS once (single barrier). Each wave owns a 96-col strip and
// streams B-frags global->VGPR (L2-hot W), register double-buffered; the hot
// loop has NO __syncthreads -> fine-grained vmcnt/lgkmcnt scheduling.
// Grid 1-D: pm = bid & 255 (XCD swizzle: same panel -> same XCD), g = bid>>8.
// ---------------------------------------------------------------------------
template <bool OUTF32>
__global__ __launch_bounds__(256) void gemm_mfma_kernel(
    const unsigned short* __restrict__ A, const unsigned short* __restrict__ Bt,
    const float* __restrict__ bias, void* __restrict__ Cout, int N,
    int sc_lim, float sc) {
  __shared__ __align__(16) unsigned short As[48 * 512];  // 48 KB: (s*24+kc)*512
  const int tid = threadIdx.x;
  const int w = tid >> 6, l = tid & 63;
  const int lm = l & 15, lq = l >> 4;
  const int bid = blockIdx.x;
  const int m0 = (bid & 255) * 32;
  const int n0w = (bid >> 8) * 384 + w * 96;

  // stage A panel: 48 chunks of 1 KB, fragment order
#pragma unroll
  for (int i = 0; i < 12; ++i) {
    const int c = w * 12 + i;            // c = s*24 + kc
    const int s = c / 24, kc = c % 24;
    load_lds16(A + (size_t)(m0 + s * 16 + lm) * KD_ + kc * 32 + lq * 8,
               &As[c * 512]);
  }
  __syncthreads();  // the only barrier

  const unsigned short* pB[6];
#pragma unroll
  for (int nb = 0; nb < 6; ++nb)
    pB[nb] = Bt + (size_t)(n0w + nb * 16 + lm) * KD_ + lq * 8;

  f32x4 acc[2][6];
#pragma unroll
  for (int s = 0; s < 2; ++s)
#pragma unroll
    for (int nb = 0; nb < 6; ++nb) acc[s][nb] = (f32x4){0.f, 0.f, 0.f, 0.f};

  bf16x8 af[2][2], bfr[2][6];
#pragma unroll
  for (int s = 0; s < 2; ++s)
    af[0][s] = *(const bf16x8*)&As[(s * 24) * 512 + l * 8];
#pragma unroll
  for (int nb = 0; nb < 6; ++nb)
    bfr[0][nb] = *(const bf16x8*)(pB[nb]);

#pragma unroll
  for (int kc = 0; kc < NKC; ++kc) {
    const int cur = kc & 1, nxt = cur ^ 1;
    if (kc + 1 < NKC) {
#pragma unroll
      for (int s = 0; s < 2; ++s)
        af[nxt][s] = *(const bf16x8*)&As[(s * 24 + kc + 1) * 512 + l * 8];
#pragma unroll
      for (int nb = 0; nb < 6; ++nb)
        bfr[nxt][nb] = *(const bf16x8*)(pB[nb] + (kc + 1) * 32);
    }
#pragma unroll
    for (int s = 0; s < 2; ++s)
#pragma unroll
      for (int nb = 0; nb < 6; ++nb)
        acc[s][nb] = __builtin_amdgcn_mfma_f32_16x16x32_bf16(
            af[cur][s], bfr[cur][nb], acc[s][nb], 0, 0, 0);
  }

#pragma unroll
  for (int s = 0; s < 2; ++s) {
    const int row = m0 + s * 16 + lq * 4;
#pragma unroll
    for (int nb = 0; nb < 6; ++nb) {
      const int col = n0w + nb * 16 + lm;
      const float bv = bias[col];
      const float mul = (col < sc_lim) ? sc : 1.f;
#pragma unroll
      for (int r = 0; r < 4; ++r) {
        float v = (acc[s][nb][r] + bv) * mul;
        if (OUTF32)
          ((float*)Cout)[(size_t)(row + r) * N + col] = v;
        else
          ((unsigned short*)Cout)[(size_t)(row + r) * N + col] = f2bf(v);
      }
    }
  }
}

// ---------------------------------------------------------------------------
// Flash causal attention, bf16 MFMA, max-free softmax (Q pre-scaled), l via
// ones-MFMA. One WAVE per block (64 thr), zero __syncthreads: K/V frags
// loaded global->VGPR (L2-hot via swizzle), P round-trips through private
// per-wave LDS (lgkmcnt only). Block = (bh, q-tile pair, 16-row slice).
// Grid 2048: bh = id & 63 (XCD locality), wq = (id>>6)&3, pi = id>>8.
// ---------------------------------------------------------------------------
__global__ __launch_bounds__(64) void attn_mfma_kernel(
    const unsigned short* __restrict__ qkv,  // [8192][2304], Q pre-scaled
    const unsigned short* __restrict__ vt,   // [64][96][1024]
    unsigned short* __restrict__ y) {        // [8192][768]
  __shared__ __align__(16) unsigned short Pt[16][72];  // pad 64->72

  const int tid = threadIdx.x;
  const int l = tid & 63;
  const int lm = l & 15, lq = l >> 4;
  const int bh = blockIdx.x & 63;
  const int wq = (blockIdx.x >> 6) & 3;
  const int pi = blockIdx.x >> 8;           // 0..7
  const int b = bh >> 3, h = bh & 7;
  const size_t bT = (size_t)b * T_;

  bf16x8 onef;
#pragma unroll
  for (int i = 0; i < 8; ++i) onef[i] = (__bf16)1.0f;

  for (int half = 0; half < 2; ++half) {
    const int qt = half ? (15 - pi) : pi;
    const int q0r = qt * 64 + wq * 16;      // this wave's 16 query rows

    bf16x8 qf[3];
    {
      const unsigned short* qp = qkv + (bT + q0r + lm) * N1_ + h * D_ + lq * 8;
      qf[0] = *(const bf16x8*)(qp);
      qf[1] = *(const bf16x8*)(qp + 32);
      qf[2] = *(const bf16x8*)(qp + 64);
    }
    f32x4 o[7];  // 6 dim-blocks + l accumulator
#pragma unroll
    for (int i = 0; i < 7; ++i) o[i] = (f32x4){0.f, 0.f, 0.f, 0.f};

    for (int jt = 0; jt <= qt; ++jt) {
      const int j0 = jt * 64;
      // issue all K-frag and V-frag loads (independent, deep in flight)
      bf16x8 kf[4][3], vf[6][2];
      {
        const unsigned short* pK =
            qkv + (bT + j0 + lm) * N1_ + C_ + h * D_ + lq * 8;
#pragma unroll
        for (int nb = 0; nb < 4; ++nb) {
          const unsigned short* p = pK + (size_t)nb * 16 * N1_;
#pragma unroll
          for (int kc = 0; kc < 3; ++kc)
            kf[nb][kc] = *(const bf16x8*)(p + kc * 32);
        }
        const unsigned short* pV =
            vt + ((size_t)bh * D_ + lm) * T_ + j0 + lq * 8;
#pragma unroll
        for (int db = 0; db < 6; ++db) {
          const unsigned short* p = pV + (size_t)db * 16 * T_;
#pragma unroll
          for (int vc = 0; vc < 2; ++vc)
            vf[db][vc] = *(const bf16x8*)(p + vc * 32);
        }
      }

      const bool diag = (jt == qt);
#pragma unroll
      for (int nb = 0; nb < 4; ++nb) {
        if (diag && nb > wq) {  // wave-uniform: block fully masked
#pragma unroll
          for (int r = 0; r < 4; ++r)
            Pt[lq * 4 + r][nb * 16 + lm] = 0;
          continue;
        }
        f32x4 a = (f32x4){0.f, 0.f, 0.f, 0.f};
#pragma unroll
        for (int kc = 0; kc < 3; ++kc)
          a = __builtin_amdgcn_mfma_f32_16x16x32_bf16(qf[kc], kf[nb][kc], a,
                                                      0, 0, 0);
#pragma unroll
        for (int r = 0; r < 4; ++r) {
          float s = a[r];
          if (diag && (nb * 16 + lm > wq * 16 + lq * 4 + r)) s = -INFINITY;
          Pt[lq * 4 + r][nb * 16 + lm] = f2bf(__expf(s));
        }
      }

      // PV: P as A-frag (private LDS round trip, lgkmcnt only)
      bf16x8 pf0 = *(const bf16x8*)&Pt[lm][lq * 8];
      bf16x8 pf1 = *(const bf16x8*)&Pt[lm][32 + lq * 8];
#pragma unroll
      for (int db = 0; db < 6; ++db) {
        o[db] = __builtin_amdgcn_mfma_f32_16x16x32_bf16(pf0, vf[db][0], o[db],
                                                        0, 0, 0);
        o[db] = __builtin_amdgcn_mfma_f32_16x16x32_bf16(pf1, vf[db][1], o[db],
                                                        0, 0, 0);
      }
      o[6] = __builtin_amdgcn_mfma_f32_16x16x32_bf16(pf0, onef, o[6], 0, 0, 0);
      o[6] = __builtin_amdgcn_mfma_f32_16x16x32_bf16(pf1, onef, o[6], 0, 0, 0);
    }

#pragma unroll
    for (int r = 0; r < 4; ++r) {
      const float inv = 1.f / o[6][r];
      const size_t row = bT + q0r + lq * 4 + r;
#pragma unroll
      for (int db = 0; db < 6; ++db)
        y[row * C_ + h * D_ + db * 16 + lm] = f2bf(o[db][r] * inv);
    }
  }
}

// ---------------------------------------------------------------------------
extern "C" void kernel_launch(void* const* d_in, const int* in_sizes, int n_in,
                              void* d_out, int out_size, void* d_ws, size_t ws_size,
                              hipStream_t stream) {
  const float* x      = (const float*)d_in[0];
  const float* W_attn = (const float*)d_in[1];
  const float* b_attn = (const float*)d_in[2];
  const float* W_proj = (const float*)d_in[3];
  const float* b_proj = (const float*)d_in[4];
  float* out = (float*)d_out;

  char* ws = (char*)d_ws;
  unsigned short* xb  = (unsigned short*)(ws);                    // 12.58 MB
  unsigned short* WaT = (unsigned short*)(ws + 12582912);         //  3.54 MB
  unsigned short* WpT = (unsigned short*)(ws + 16121856);         //  1.18 MB
  unsigned short* qkv = (unsigned short*)(ws + 17301504);         // 37.75 MB
  unsigned short* vt  = (unsigned short*)(ws + 55050240);         // 12.58 MB
  unsigned short* yb  = (unsigned short*)(ws + 67633152);         // 12.58 MB

  const float qscale = 0.10206207261596577f;  // 1/sqrt(96)

  cvt_bf16_kernel<<<(M_ * C_) / 1024, 256, 0, stream>>>(x, xb, M_ * C_);
  w_transpose_kernel<<<dim3(C_ / 32, N1_ / 32), 256, 0, stream>>>(W_attn, WaT, C_, N1_);
  w_transpose_kernel<<<dim3(C_ / 32, C_ / 32), 256, 0, stream>>>(W_proj, WpT, C_, C_);

  // qkv = x @ W_attn + b_attn; Q cols pre-scaled by 1/sqrt(D).
  // grid: 256 M-panels x 6 N-groups of 384
  gemm_mfma_kernel<false><<<256 * 6, 256, 0, stream>>>(
      xb, WaT, b_attn, qkv, N1_, C_, qscale);
  v_transpose_kernel<<<dim3(M_ / 64, 24), 256, 0, stream>>>(qkv, vt);
  // attn: 2048 one-wave blocks, bh = id & 63 for XCD locality
  attn_mfma_kernel<<<2048, 64, 0, stream>>>(qkv, vt, yb);
  // proj: 256 M-panels x 2 N-groups of 384
  gemm_mfma_kernel<true><<<256 * 2, 256, 0, stream>>>(
      yb, WpT, b_proj, out, C_, 0, 1.f);
}

// Round 8
// 221.161 us; speedup vs baseline: 1.5496x; 1.5496x over previous
//
#include <hip/hip_runtime.h>
#include <math.h>

#define B_ 8
#define T_ 1024
#define C_ 768
#define H_ 8
#define D_ 96
#define M_ (B_ * T_)     // 8192 tokens
#define N1_ (3 * C_)     // 2304
#define KD_ 768          // K of both GEMMs

typedef __bf16 bf16x8 __attribute__((ext_vector_type(8)));
typedef float f32x4 __attribute__((ext_vector_type(4)));
typedef float f32x16 __attribute__((ext_vector_type(16)));

__device__ __forceinline__ unsigned short f2bf(float f) {
  unsigned int u = __float_as_uint(f);
  u += 0x7FFF + ((u >> 16) & 1);          // round-to-nearest-even
  return (unsigned short)(u >> 16);
}

// async global->LDS, 16B per lane; LDS dest = uniform base + lane*16
__device__ __forceinline__ void load_lds16(const void* g, void* l) {
  __builtin_amdgcn_global_load_lds(
      (const __attribute__((address_space(1))) unsigned int*)g,
      (__attribute__((address_space(3))) unsigned int*)l, 16, 0, 0);
}

// ---------------------------------------------------------------------------
// fp32 -> bf16 elementwise (for x)
// ---------------------------------------------------------------------------
__global__ __launch_bounds__(256) void cvt_bf16_kernel(
    const float* __restrict__ in, unsigned short* __restrict__ out, int n) {
  int i = (blockIdx.x * 256 + threadIdx.x) * 4;
  if (i + 3 < n) {
    float4 v = *(const float4*)(in + i);
    ushort4 o;
    o.x = f2bf(v.x); o.y = f2bf(v.y); o.z = f2bf(v.z); o.w = f2bf(v.w);
    *(ushort4*)(out + i) = o;
  }
}

// ---------------------------------------------------------------------------
// Both weight transposes in one launch. W [Kd][Nd] fp32 -> WT [Nd][Kd] bf16.
// blocks 0..1727: W_attn (24x72); 1728..2303: W_proj (24x24).
// ---------------------------------------------------------------------------
__global__ __launch_bounds__(256) void w_transpose2_kernel(
    const float* __restrict__ Wa, unsigned short* __restrict__ WaT,
    const float* __restrict__ Wp, unsigned short* __restrict__ WpT) {
  __shared__ float Lt[32][33];
  int bid = blockIdx.x;
  const float* W; unsigned short* WT; int Nd;
  if (bid < 1728) { W = Wa; WT = WaT; Nd = N1_; }
  else            { W = Wp; WT = WpT; Nd = C_; bid -= 1728; }
  const int r0 = (bid % 24) * 32;   // Kd
  const int c0 = (bid / 24) * 32;   // Nd
#pragma unroll
  for (int i = 0; i < 4; ++i) {
    int e = threadIdx.x + 256 * i;
    int r = e >> 5, c = e & 31;
    Lt[r][c] = W[(size_t)(r0 + r) * Nd + c0 + c];
  }
  __syncthreads();
#pragma unroll
  for (int i = 0; i < 4; ++i) {
    int e = threadIdx.x + 256 * i;
    int rr = e >> 5, cc = e & 31;
    WT[(size_t)(c0 + rr) * KD_ + r0 + cc] = f2bf(Lt[cc][rr]);
  }
}

// ---------------------------------------------------------------------------
// bf16 MFMA GEMM on 32x32x16, double-buffered LDS (BK=32), load_lds staging.
// Block: (2*WM32*32) x 128, 256 thr, 2x2 waves; wave tile (WM32*32) x 64
// as WM32 x 2 blocks of 32x32. A/B frag: lane l = [row=l&31][k=(l>>5)*8..+7].
// C/D: col = lane&31, row = (r&3) + 8*(r>>2) + 4*(lane>>5)  [m74/m101].
// VSCAT (qkv only): col-blocks >= 1536 (V) scatter to vt[bh][d][t] instead
// of the row-major store (attn never reads qkv's V region).
// Grid 1-D, XCD swizzle: m-panel = bid & mmask.
// ---------------------------------------------------------------------------
template <int WM32, bool OUTF32, bool VSCAT>
__global__ __launch_bounds__(256) void gemm_mfma_kernel(
    const unsigned short* __restrict__ A, const unsigned short* __restrict__ Bt,
    const float* __restrict__ bias, void* __restrict__ Cout,
    unsigned short* __restrict__ vt, int N,
    int sc_lim, float sc, int mmask, int mshift) {
  constexpr int AS2 = 2 * WM32;        // A 32-row blocks per tile
  constexpr int NC  = (AS2 + 4) * 2;   // 1KB chunks per buffer (k-halves)
  constexpr int CPW = NC / 4;          // chunks staged per wave
  __shared__ __align__(16) unsigned short Sb[2][NC * 512];
  const int tid = threadIdx.x;
  const int w = tid >> 6, l = tid & 63;
  const int l31 = l & 31, lh = l >> 5;
  const int bid = blockIdx.x;
  const int m0 = (bid & mmask) * (AS2 * 32), n0 = (bid >> mshift) * 128;
  const int wrb = (w >> 1) * WM32;     // wave A-block base
  const int wnb = (w & 1) * 2;         // wave B-block base

  f32x16 acc[WM32][2];
#pragma unroll
  for (int i = 0; i < WM32; ++i)
#pragma unroll
    for (int j = 0; j < 2; ++j)
#pragma unroll
      for (int r = 0; r < 16; ++r) acc[i][j][r] = 0.f;

  const unsigned short* gp[CPW];
#pragma unroll
  for (int i = 0; i < CPW; ++i) {
    const int c = w * CPW + i;
    const int pr = c >> 1, kh = c & 1;
    gp[i] = (pr < AS2)
        ? A  + (size_t)(m0 + pr * 32 + l31) * KD_ + kh * 16 + lh * 8
        : Bt + (size_t)(n0 + (pr - AS2) * 32 + l31) * KD_ + kh * 16 + lh * 8;
  }

  // prologue: stage k0=0 into buffer 0
#pragma unroll
  for (int i = 0; i < CPW; ++i) {
    load_lds16(gp[i], &Sb[0][(w * CPW + i) * 512]);
    gp[i] += 32;
  }

  int cur = 0;
  for (int k0 = 0; k0 < KD_; k0 += 32) {
    __syncthreads();  // buf[cur] ready; prev compute done
    if (k0 + 32 < KD_) {
#pragma unroll
      for (int i = 0; i < CPW; ++i) {
        load_lds16(gp[i], &Sb[cur ^ 1][(w * CPW + i) * 512]);
        gp[i] += 32;
      }
    }
#pragma unroll
    for (int kh = 0; kh < 2; ++kh) {
      bf16x8 af[WM32], bfr[2];
#pragma unroll
      for (int mi = 0; mi < WM32; ++mi)
        af[mi] = *(const bf16x8*)&Sb[cur][((wrb + mi) * 2 + kh) * 512 + l * 8];
#pragma unroll
      for (int ni = 0; ni < 2; ++ni)
        bfr[ni] = *(const bf16x8*)&Sb[cur][((AS2 + wnb + ni) * 2 + kh) * 512 + l * 8];
#pragma unroll
      for (int mi = 0; mi < WM32; ++mi)
#pragma unroll
        for (int ni = 0; ni < 2; ++ni)
          acc[mi][ni] = __builtin_amdgcn_mfma_f32_32x32x16_bf16(
              af[mi], bfr[ni], acc[mi][ni], 0, 0, 0);
    }
    cur ^= 1;
  }

  const bool vblock = VSCAT && (n0 >= 1536);
#pragma unroll
  for (int mi = 0; mi < WM32; ++mi) {
    const int rowb = m0 + (wrb + mi) * 32 + 4 * lh;
#pragma unroll
    for (int ni = 0; ni < 2; ++ni) {
      const int col = n0 + (wnb + ni) * 32 + l31;
      const float bv = bias[col];
      if (!vblock) {
        const float mul = (col < sc_lim) ? sc : 1.f;
#pragma unroll
        for (int r = 0; r < 16; ++r) {
          const int row = rowb + (r & 3) + 8 * (r >> 2);
          float v = (acc[mi][ni][r] + bv) * mul;
          if (OUTF32)
            ((float*)Cout)[(size_t)row * N + col] = v;
          else
            ((unsigned short*)Cout)[(size_t)row * N + col] = f2bf(v);
        }
      } else {
        // V scatter: col-1536 = h*96+d; token = row -> vt[(b*8+h)*96+d][t]
        const int x = col - 1536;
        const int h = x / 96, d = x % 96;
#pragma unroll
        for (int r = 0; r < 16; ++r) {
          const int row = rowb + (r & 3) + 8 * (r >> 2);
          const int bb = row >> 10, t = row & 1023;
          vt[((size_t)(bb * H_ + h) * D_ + d) * T_ + t] = f2bf(acc[mi][ni][r] + bv);
        }
      }
    }
  }
}

// ---------------------------------------------------------------------------
// Flash causal attention (unchanged R6): bf16 MFMA 16x16x32, max-free softmax
// (Q pre-scaled), l via ones-MFMA, paired q-tiles (17 key-tiles/block),
// K/V double-buffered LDS, XCD swizzle bh = id & 63.
// ---------------------------------------------------------------------------
__global__ __launch_bounds__(256) void attn_mfma_kernel(
    const unsigned short* __restrict__ qkv,  // [8192][2304], Q pre-scaled
    const unsigned short* __restrict__ vt,   // [64][96][1024]
    unsigned short* __restrict__ y) {        // [8192][768]
  __shared__ __align__(16) unsigned short KV[2][24 * 512];  // 48 KB
  __shared__ __align__(16) unsigned short Pt[4][16][72];    // pad 64->72

  const int tid = threadIdx.x;
  const int w = tid >> 6, l = tid & 63;
  const int lm = l & 15, lq = l >> 4;
  const int bh = blockIdx.x & 63, pi = blockIdx.x >> 6;
  const int b = bh >> 3, h = bh & 7;
  const size_t bT = (size_t)b * T_;

  bf16x8 onef;
#pragma unroll
  for (int i = 0; i < 8; ++i) onef[i] = (__bf16)1.0f;

  auto issue = [&](int j0, int buf) {
#pragma unroll
    for (int i = 0; i < 6; ++i) {
      const int c = w * 6 + i;
      const unsigned short* g;
      if (c < 12) {  // K chunk (B-frag for QK^T)
        const int kc = c >> 2, nb = c & 3;
        g = qkv + (bT + j0 + nb * 16 + lm) * N1_ + C_ + h * D_ + kc * 32 + lq * 8;
      } else {       // V chunk (B-frag for PV, from VT)
        const int cv = c - 12;
        const int db = cv >> 1, vc = cv & 1;
        g = vt + ((size_t)bh * D_ + db * 16 + lm) * T_ + j0 + vc * 32 + lq * 8;
      }
      load_lds16(g, &KV[buf][c * 512]);
    }
  };

  int cur = 0;
  issue(0, 0);

  for (int half = 0; half < 2; ++half) {
    const int qt = half ? (15 - pi) : pi;
    const int q0 = qt * 64;

    bf16x8 qf[3];
    {
      const unsigned short* qp =
          qkv + (bT + q0 + w * 16 + lm) * N1_ + h * D_ + lq * 8;
      qf[0] = *(const bf16x8*)(qp);
      qf[1] = *(const bf16x8*)(qp + 32);
      qf[2] = *(const bf16x8*)(qp + 64);
    }
    f32x4 o[7];  // 6 dim-blocks + l accumulator
#pragma unroll
    for (int i = 0; i < 7; ++i) o[i] = (f32x4){0.f, 0.f, 0.f, 0.f};

    for (int jt = 0; jt <= qt; ++jt) {
      __syncthreads();
      if (jt < qt)          issue((jt + 1) * 64, cur ^ 1);
      else if (half == 0)   issue(0, cur ^ 1);

      const bool diag = (jt == qt);
#pragma unroll
      for (int nb = 0; nb < 4; ++nb) {
        if (diag && nb > w) {
#pragma unroll
          for (int r = 0; r < 4; ++r)
            Pt[w][lq * 4 + r][nb * 16 + lm] = 0;
          continue;
        }
        f32x4 a = (f32x4){0.f, 0.f, 0.f, 0.f};
#pragma unroll
        for (int kc = 0; kc < 3; ++kc) {
          bf16x8 kf = *(const bf16x8*)&KV[cur][(kc * 4 + nb) * 512 + l * 8];
          a = __builtin_amdgcn_mfma_f32_16x16x32_bf16(qf[kc], kf, a, 0, 0, 0);
        }
#pragma unroll
        for (int r = 0; r < 4; ++r) {
          float s = a[r];
          if (diag && (nb * 16 + lm > w * 16 + lq * 4 + r)) s = -INFINITY;
          Pt[w][lq * 4 + r][nb * 16 + lm] = f2bf(__expf(s));
        }
      }

      bf16x8 pf0 = *(const bf16x8*)&Pt[w][lm][lq * 8];
      bf16x8 pf1 = *(const bf16x8*)&Pt[w][lm][32 + lq * 8];
#pragma unroll
      for (int db = 0; db < 6; ++db) {
        bf16x8 vf0 = *(const bf16x8*)&KV[cur][(12 + db * 2 + 0) * 512 + l * 8];
        bf16x8 vf1 = *(const bf16x8*)&KV[cur][(12 + db * 2 + 1) * 512 + l * 8];
        o[db] = __builtin_amdgcn_mfma_f32_16x16x32_bf16(pf0, vf0, o[db], 0, 0, 0);
        o[db] = __builtin_amdgcn_mfma_f32_16x16x32_bf16(pf1, vf1, o[db], 0, 0, 0);
      }
      o[6] = __builtin_amdgcn_mfma_f32_16x16x32_bf16(pf0, onef, o[6], 0, 0, 0);
      o[6] = __builtin_amdgcn_mfma_f32_16x16x32_bf16(pf1, onef, o[6], 0, 0, 0);
      cur ^= 1;
    }

#pragma unroll
    for (int r = 0; r < 4; ++r) {
      const float inv = 1.f / o[6][r];
      const size_t row = bT + q0 + w * 16 + lq * 4 + r;
#pragma unroll
      for (int db = 0; db < 6; ++db)
        y[row * C_ + h * D_ + db * 16 + lm] = f2bf(o[db][r] * inv);
    }
  }
}

// ---------------------------------------------------------------------------
extern "C" void kernel_launch(void* const* d_in, const int* in_sizes, int n_in,
                              void* d_out, int out_size, void* d_ws, size_t ws_size,
                              hipStream_t stream) {
  const float* x      = (const float*)d_in[0];
  const float* W_attn = (const float*)d_in[1];
  const float* b_attn = (const float*)d_in[2];
  const float* W_proj = (const float*)d_in[3];
  const float* b_proj = (const float*)d_in[4];
  float* out = (float*)d_out;

  char* ws = (char*)d_ws;
  unsigned short* xb  = (unsigned short*)(ws);                    // 12.58 MB
  unsigned short* WaT = (unsigned short*)(ws + 12582912);         //  3.54 MB
  unsigned short* WpT = (unsigned short*)(ws + 16121856);         //  1.18 MB
  unsigned short* qkv = (unsigned short*)(ws + 17301504);         // 37.75 MB
  unsigned short* vt  = (unsigned short*)(ws + 55050240);         // 12.58 MB
  unsigned short* yb  = (unsigned short*)(ws + 67633152);         // 12.58 MB

  const float qscale = 0.10206207261596577f;  // 1/sqrt(96)

  cvt_bf16_kernel<<<(M_ * C_) / 1024, 256, 0, stream>>>(x, xb, M_ * C_);
  w_transpose2_kernel<<<2304, 256, 0, stream>>>(W_attn, WaT, W_proj, WpT);

  // qkv = x @ W_attn + b_attn (Q cols pre-scaled; V cols scattered to vt)
  gemm_mfma_kernel<2, false, true><<<(N1_ / 128) * (M_ / 128), 256, 0, stream>>>(
      xb, WaT, b_attn, qkv, vt, N1_, C_, qscale, 63, 6);
  // attn: 512 blocks, bh = id & 63 for XCD locality
  attn_mfma_kernel<<<8 * B_ * H_, 256, 0, stream>>>(qkv, vt, yb);
  // proj: 64x128 tiles, 128 m-panels
  gemm_mfma_kernel<1, true, false><<<(C_ / 128) * (M_ / 64), 256, 0, stream>>>(
      yb, WpT, b_proj, out, nullptr, C_, 0, 1.f, 127, 7);
}